// Round 15
// baseline (157.647 us; speedup 1.0000x reference)
//
#include <hip/hip_runtime.h>
#include <math.h>

// MX two-level fp4-e2m1 quantize->dequantize, (8192,8192) fp32.
//
// DECISION MATH FROZEN (bitwise-verified r13, absmax=0):
//   n = RN32( RN32(x / s32) / s128 )   -- subgroup scale FIRST
//   q = sign(n) * floor(|2n| + 0.5) / 2   (faithful f32 sym round)
//   out = (q * s32) * s128
//   s32 = m + 1e-8f, s128 = g + 1e-8f (f32 adds, as reference)
//
// r15 = r14 with the nontemporal-store compile fix: clang's builtin needs a
// native vector type, not HIP_vector_type<float,4> — use ext_vector_type(4).
// Perf change vs r13: 32 B/lane (2 float4), nontemporal streaming stores.
// Lane L covers elements 8L..8L+7; subgroup(32) = 4 lanes (xor 1,2);
// group(128) = 16 lanes (xor 4,8); both divide 64 so reductions stay in-wave.

typedef float f32x4 __attribute__((ext_vector_type(4)));

__device__ __forceinline__ float qdq_elem(float x, float s32f, float s128f) {
    float n = (x / s32f) / s128f;                 // frozen seq IEEE divides
    float q = copysignf(floorf(2.0f * fabsf(n) + 0.5f) * 0.5f, n);
    return (q * s32f) * s128f;                    // frozen dequant assoc
}

__global__ __launch_bounds__(256) void mx2q_kernel(const float* __restrict__ in,
                                                   float* __restrict__ out,
                                                   int n8) {
    const f32x4* in4 = reinterpret_cast<const f32x4*>(in);
    f32x4* out4 = reinterpret_cast<f32x4*>(out);
    int idx = blockIdx.x * 256 + threadIdx.x;
    int stride = gridDim.x * 256;
    for (; idx < n8; idx += stride) {
        size_t b = 2 * (size_t)idx;
        f32x4 v0 = in4[b];
        f32x4 v1 = in4[b + 1];

        float a0 = fmaxf(fmaxf(fabsf(v0.x), fabsf(v0.y)),
                         fmaxf(fabsf(v0.z), fabsf(v0.w)));
        float a1 = fmaxf(fmaxf(fabsf(v1.x), fabsf(v1.y)),
                         fmaxf(fabsf(v1.z), fabsf(v1.w)));
        float a = fmaxf(a0, a1);

        // 32-elem subgroup = 4 consecutive lanes (8 floats/lane)
        float m = a;
        m = fmaxf(m, __shfl_xor(m, 1));
        m = fmaxf(m, __shfl_xor(m, 2));
        // 128-elem group = 16 consecutive lanes
        float g = m;
        g = fmaxf(g, __shfl_xor(g, 4));
        g = fmaxf(g, __shfl_xor(g, 8));

        float s32f  = m + 1e-8f;
        float s128f = g + 1e-8f;

        f32x4 r0, r1;
        r0.x = qdq_elem(v0.x, s32f, s128f);
        r0.y = qdq_elem(v0.y, s32f, s128f);
        r0.z = qdq_elem(v0.z, s32f, s128f);
        r0.w = qdq_elem(v0.w, s32f, s128f);
        r1.x = qdq_elem(v1.x, s32f, s128f);
        r1.y = qdq_elem(v1.y, s32f, s128f);
        r1.z = qdq_elem(v1.z, s32f, s128f);
        r1.w = qdq_elem(v1.w, s32f, s128f);

        __builtin_nontemporal_store(r0, &out4[b]);
        __builtin_nontemporal_store(r1, &out4[b + 1]);
    }
}

extern "C" void kernel_launch(void* const* d_in, const int* in_sizes, int n_in,
                              void* d_out, int out_size, void* d_ws, size_t ws_size,
                              hipStream_t stream) {
    const float* x = (const float*)d_in[0];
    float* out = (float*)d_out;
    int n = in_sizes[0];              // 8192*8192
    int n8 = n / 8;                   // 32-byte chunks (2 float4)
    long long blocks_ll = ((long long)n8 + 255) / 256;
    int blocks = (int)(blocks_ll < 2048 ? blocks_ll : 2048);
    hipLaunchKernelGGL(mx2q_kernel, dim3(blocks), dim3(256), 0, stream,
                       x, out, n8);
}

// Round 16
// 104.557 us; speedup vs baseline: 1.5078x; 1.5078x over previous
//
#include <hip/hip_runtime.h>
#include <math.h>

// MX two-level fp4-e2m1 quantize->dequantize, (8192,8192) fp32.
//
// DECISION MATH FROZEN (bitwise-verified r13, absmax=0):
//   n = RN32( RN32(x / s32) / s128 )   -- subgroup scale FIRST
//   q = sign(n) * floor(|2n| + 0.5) / 2   (faithful f32 sym round)
//   out = (q * s32) * s128
//   s32 = m + 1e-8f, s128 = g + 1e-8f
//
// r16 = r13 structure (1 float4/lane, perfectly coalesced, plain stores)
// + MLP fix: exact trip count passed in (n4 = 2^24, grid = 2^19 lanes ->
// 32 trips) with #pragma unroll 4 so 4 independent loads stay in flight.
// r15 lessons: 2-chunk/lane stride breaks coalescing (2x transactions);
// NT 16B stores defeat L2 write aggregation (WRITE_SIZE 445MB vs 268MB).

__device__ __forceinline__ float qdq_elem(float x, float s32f, float s128f) {
    float n = (x / s32f) / s128f;                 // frozen seq IEEE divides
    float q = copysignf(floorf(2.0f * fabsf(n) + 0.5f) * 0.5f, n);
    return (q * s32f) * s128f;                    // frozen dequant assoc
}

__global__ __launch_bounds__(256) void mx2q_kernel(const float* __restrict__ in,
                                                   float* __restrict__ out,
                                                   int iters, int stride) {
    const float4* in4 = reinterpret_cast<const float4*>(in);
    float4* out4 = reinterpret_cast<float4*>(out);
    int idx = blockIdx.x * 256 + threadIdx.x;
#pragma unroll 4
    for (int it = 0; it < iters; ++it, idx += stride) {
        float4 v = in4[idx];
        float a = fmaxf(fmaxf(fabsf(v.x), fabsf(v.y)),
                        fmaxf(fabsf(v.z), fabsf(v.w)));
        // 32-elem subgroup = 8 consecutive lanes (4 floats/lane)
        float m = a;
        m = fmaxf(m, __shfl_xor(m, 1));
        m = fmaxf(m, __shfl_xor(m, 2));
        m = fmaxf(m, __shfl_xor(m, 4));
        // 128-elem group = 32 consecutive lanes
        float g = m;
        g = fmaxf(g, __shfl_xor(g, 8));
        g = fmaxf(g, __shfl_xor(g, 16));

        float s32f  = m + 1e-8f;
        float s128f = g + 1e-8f;

        float4 r;
        r.x = qdq_elem(v.x, s32f, s128f);
        r.y = qdq_elem(v.y, s32f, s128f);
        r.z = qdq_elem(v.z, s32f, s128f);
        r.w = qdq_elem(v.w, s32f, s128f);
        out4[idx] = r;
    }
}

// generic tail version (grid-stride) for sizes not divisible by the grid
__global__ __launch_bounds__(256) void mx2q_kernel_gs(const float* __restrict__ in,
                                                      float* __restrict__ out,
                                                      int n4) {
    const float4* in4 = reinterpret_cast<const float4*>(in);
    float4* out4 = reinterpret_cast<float4*>(out);
    int idx = blockIdx.x * 256 + threadIdx.x;
    int stride = gridDim.x * 256;
    for (; idx < n4; idx += stride) {
        float4 v = in4[idx];
        float a = fmaxf(fmaxf(fabsf(v.x), fabsf(v.y)),
                        fmaxf(fabsf(v.z), fabsf(v.w)));
        float m = a;
        m = fmaxf(m, __shfl_xor(m, 1));
        m = fmaxf(m, __shfl_xor(m, 2));
        m = fmaxf(m, __shfl_xor(m, 4));
        float g = m;
        g = fmaxf(g, __shfl_xor(g, 8));
        g = fmaxf(g, __shfl_xor(g, 16));
        float s32f  = m + 1e-8f;
        float s128f = g + 1e-8f;
        float4 r;
        r.x = qdq_elem(v.x, s32f, s128f);
        r.y = qdq_elem(v.y, s32f, s128f);
        r.z = qdq_elem(v.z, s32f, s128f);
        r.w = qdq_elem(v.w, s32f, s128f);
        out4[idx] = r;
    }
}

extern "C" void kernel_launch(void* const* d_in, const int* in_sizes, int n_in,
                              void* d_out, int out_size, void* d_ws, size_t ws_size,
                              hipStream_t stream) {
    const float* x = (const float*)d_in[0];
    float* out = (float*)d_out;
    int n = in_sizes[0];              // 8192*8192 = 2^26
    int n4 = n / 4;                   // 2^24 float4 chunks
    const int blocks = 2048;          // 2^19 lanes, 8 blocks/CU
    int lanes = blocks * 256;
    if (n4 % lanes == 0) {
        int iters = n4 / lanes;       // 32 for the bench shape
        hipLaunchKernelGGL(mx2q_kernel, dim3(blocks), dim3(256), 0, stream,
                           x, out, iters, lanes);
    } else {
        long long blocks_ll = ((long long)n4 + 255) / 256;
        int b = (int)(blocks_ll < 2048 ? blocks_ll : 2048);
        hipLaunchKernelGGL(mx2q_kernel_gs, dim3(b), dim3(256), 0, stream,
                           x, out, n4);
    }
}

// Round 17
// 87.057 us; speedup vs baseline: 1.8108x; 1.2010x over previous
//
#include <hip/hip_runtime.h>
#include <math.h>

// MX two-level fp4-e2m1 quantize->dequantize, (8192,8192) fp32.
//
// DECISION MATH FROZEN (bitwise-verified r13, absmax=0):
//   n = RN32( RN32(x / s32) / s128 )   -- subgroup scale FIRST
//   q = sign(n) * floor(|2n| + 0.5) / 2   (faithful f32 sym round)
//   out = (q * s32) * s128
//   s32 = m + 1e-8f, s128 = g + 1e-8f
//
// r17 = r16 (coalesced 1-float4/lane, unroll-4 exact-trip) + NONTEMPORAL
// coalesced stores. Rationale: output is write-once (zero cache value);
// NT stores keep the 268MB input resident in the 256MB L3 across replays
// (r15 showed FETCH already only 134MB with write-evictions). r15's NT
// regression was the UNCOALESCED stride (WRITE_SIZE 435MB=1.66x amplified,
// partial sectors), not NT itself; coalesced NT writes full lines.

typedef float f32x4 __attribute__((ext_vector_type(4)));

__device__ __forceinline__ float qdq_elem(float x, float s32f, float s128f) {
    float n = (x / s32f) / s128f;                 // frozen seq IEEE divides
    float q = copysignf(floorf(2.0f * fabsf(n) + 0.5f) * 0.5f, n);
    return (q * s32f) * s128f;                    // frozen dequant assoc
}

__global__ __launch_bounds__(256) void mx2q_kernel(const float* __restrict__ in,
                                                   float* __restrict__ out,
                                                   int iters, int stride) {
    const f32x4* in4 = reinterpret_cast<const f32x4*>(in);
    f32x4* out4 = reinterpret_cast<f32x4*>(out);
    int idx = blockIdx.x * 256 + threadIdx.x;
#pragma unroll 4
    for (int it = 0; it < iters; ++it, idx += stride) {
        f32x4 v = in4[idx];
        float a = fmaxf(fmaxf(fabsf(v.x), fabsf(v.y)),
                        fmaxf(fabsf(v.z), fabsf(v.w)));
        // 32-elem subgroup = 8 consecutive lanes (4 floats/lane)
        float m = a;
        m = fmaxf(m, __shfl_xor(m, 1));
        m = fmaxf(m, __shfl_xor(m, 2));
        m = fmaxf(m, __shfl_xor(m, 4));
        // 128-elem group = 32 consecutive lanes
        float g = m;
        g = fmaxf(g, __shfl_xor(g, 8));
        g = fmaxf(g, __shfl_xor(g, 16));

        float s32f  = m + 1e-8f;
        float s128f = g + 1e-8f;

        f32x4 r;
        r.x = qdq_elem(v.x, s32f, s128f);
        r.y = qdq_elem(v.y, s32f, s128f);
        r.z = qdq_elem(v.z, s32f, s128f);
        r.w = qdq_elem(v.w, s32f, s128f);
        __builtin_nontemporal_store(r, &out4[idx]);   // coalesced NT store
    }
}

// generic tail version (grid-stride) for sizes not divisible by the grid
__global__ __launch_bounds__(256) void mx2q_kernel_gs(const float* __restrict__ in,
                                                      float* __restrict__ out,
                                                      int n4) {
    const f32x4* in4 = reinterpret_cast<const f32x4*>(in);
    f32x4* out4 = reinterpret_cast<f32x4*>(out);
    int idx = blockIdx.x * 256 + threadIdx.x;
    int stride = gridDim.x * 256;
    for (; idx < n4; idx += stride) {
        f32x4 v = in4[idx];
        float a = fmaxf(fmaxf(fabsf(v.x), fabsf(v.y)),
                        fmaxf(fabsf(v.z), fabsf(v.w)));
        float m = a;
        m = fmaxf(m, __shfl_xor(m, 1));
        m = fmaxf(m, __shfl_xor(m, 2));
        m = fmaxf(m, __shfl_xor(m, 4));
        float g = m;
        g = fmaxf(g, __shfl_xor(g, 8));
        g = fmaxf(g, __shfl_xor(g, 16));
        float s32f  = m + 1e-8f;
        float s128f = g + 1e-8f;
        f32x4 r;
        r.x = qdq_elem(v.x, s32f, s128f);
        r.y = qdq_elem(v.y, s32f, s128f);
        r.z = qdq_elem(v.z, s32f, s128f);
        r.w = qdq_elem(v.w, s32f, s128f);
        __builtin_nontemporal_store(r, &out4[idx]);
    }
}

extern "C" void kernel_launch(void* const* d_in, const int* in_sizes, int n_in,
                              void* d_out, int out_size, void* d_ws, size_t ws_size,
                              hipStream_t stream) {
    const float* x = (const float*)d_in[0];
    float* out = (float*)d_out;
    int n = in_sizes[0];              // 8192*8192 = 2^26
    int n4 = n / 4;                   // 2^24 float4 chunks
    const int blocks = 2048;          // 8 blocks/CU = 32 waves/CU (max occ)
    int lanes = blocks * 256;
    if (n4 % lanes == 0) {
        int iters = n4 / lanes;       // 32 for the bench shape
        hipLaunchKernelGGL(mx2q_kernel, dim3(blocks), dim3(256), 0, stream,
                           x, out, iters, lanes);
    } else {
        long long blocks_ll = ((long long)n4 + 255) / 256;
        int b = (int)(blocks_ll < 2048 ? blocks_ll : 2048);
        hipLaunchKernelGGL(mx2q_kernel_gs, dim3(b), dim3(256), 0, stream,
                           x, out, n4);
    }
}

// Round 18
// 85.428 us; speedup vs baseline: 1.8454x; 1.0191x over previous
//
#include <hip/hip_runtime.h>
#include <math.h>

// MX two-level fp4-e2m1 quantize->dequantize, (8192,8192) fp32.
//
// DECISION MATH FROZEN (bitwise-verified r13/r16/r17, absmax=0):
//   n = RN32( RN32(x / s32) / s128 )   (subgroup scale FIRST)
//   q = sign(n) * floor(|2n| + 0.5) / 2
//   out = (q * s32) * s128;  s32 = m + 1e-8f, s128 = g + 1e-8f
//
// r18: replace the two per-element IEEE divides with a PROVABLY-BITWISE
// per-subgroup threshold compare (RN32 is monotone; each rounding layer
// converts to an exact-real cutoff representable in f64):
//   up <=> |n| >= 0.25-2^-26            (sym floor boundary, tie-even down)
//      <=> |n1| >  P  = T1*s128, T1 = 0.25 - 3*2^-27   (25b x 24b exact)
//      <=> |n1| >= c  = succ32(P)       (P never f32: odd >=25b significand)
//      <=> |x|/s32 vs t2 = mid(pred(c),c)  (odd 25-bit significand)
//      <=> |x| >  Q  = t2*s32           (49-bit exact f64; tie IMPOSSIBLE:
//                                        Q has >=25 sig bits, f32 has 24)
// Guard: fast path needs floor<=1, i.e. |n| <= RN32(1/s128) < 0.75-eps;
// s128f >= 1.4f guarantees it (|x|<=m<=s32 => |n1|<=1). Else frozen
// divide path (covers all-zero/degenerate groups; never taken on data).
// Perf r17 lesson kept: coalesced NT stores (WRITE 268MB unamplified).

typedef float f32x4 __attribute__((ext_vector_type(4)));

__device__ __forceinline__ float qdq_elem(float x, float s32f, float s128f) {
    float n = (x / s32f) / s128f;                 // frozen seq IEEE divides
    float q = copysignf(floorf(2.0f * fabsf(n) + 0.5f) * 0.5f, n);
    return (q * s32f) * s128f;                    // frozen dequant assoc
}

__global__ __launch_bounds__(256) void mx2q_kernel(const float* __restrict__ in,
                                                   float* __restrict__ out,
                                                   int iters, int stride) {
    const f32x4* in4 = reinterpret_cast<const f32x4*>(in);
    f32x4* out4 = reinterpret_cast<f32x4*>(out);
    int idx = blockIdx.x * 256 + threadIdx.x;
#pragma unroll 4
    for (int it = 0; it < iters; ++it, idx += stride) {
        f32x4 v = in4[idx];
        float a = fmaxf(fmaxf(fabsf(v.x), fabsf(v.y)),
                        fmaxf(fabsf(v.z), fabsf(v.w)));
        // 32-elem subgroup = 8 consecutive lanes (4 floats/lane)
        float m = a;
        m = fmaxf(m, __shfl_xor(m, 1));
        m = fmaxf(m, __shfl_xor(m, 2));
        m = fmaxf(m, __shfl_xor(m, 4));
        // 128-elem group = 32 consecutive lanes
        float g = m;
        g = fmaxf(g, __shfl_xor(g, 8));
        g = fmaxf(g, __shfl_xor(g, 16));

        float s32f  = m + 1e-8f;
        float s128f = g + 1e-8f;

        f32x4 r;
        if (s128f >= 1.4f) {
            // per-subgroup exact threshold (all steps exact in f64)
            const double T1 = 0.25 - 3.0 / 134217728.0;   // 0.25 - 3*2^-27
            double P  = T1 * (double)s128f;               // exact (25bx24b)
            float  cf = (float)P;                         // RN32(P)
            float  c  = ((double)cf > P)
                          ? cf
                          : __uint_as_float(__float_as_uint(cf) + 1u);
            float  pc = __uint_as_float(__float_as_uint(c) - 1u);
            double t2 = 0.5 * ((double)pc + (double)c);   // exact midpoint
            double Q  = t2 * (double)s32f;                // exact (25bx24b)
            float  dq = (0.5f * s32f) * s128f;            // |out| for q=0.5

            r.x = ((double)fabsf(v.x) > Q) ? copysignf(dq, v.x)
                                           : copysignf(0.0f, v.x);
            r.y = ((double)fabsf(v.y) > Q) ? copysignf(dq, v.y)
                                           : copysignf(0.0f, v.y);
            r.z = ((double)fabsf(v.z) > Q) ? copysignf(dq, v.z)
                                           : copysignf(0.0f, v.z);
            r.w = ((double)fabsf(v.w) > Q) ? copysignf(dq, v.w)
                                           : copysignf(0.0f, v.w);
        } else {
            r.x = qdq_elem(v.x, s32f, s128f);
            r.y = qdq_elem(v.y, s32f, s128f);
            r.z = qdq_elem(v.z, s32f, s128f);
            r.w = qdq_elem(v.w, s32f, s128f);
        }
        __builtin_nontemporal_store(r, &out4[idx]);   // coalesced NT store
    }
}

// generic tail version (grid-stride, frozen divide path) for odd sizes
__global__ __launch_bounds__(256) void mx2q_kernel_gs(const float* __restrict__ in,
                                                      float* __restrict__ out,
                                                      int n4) {
    const f32x4* in4 = reinterpret_cast<const f32x4*>(in);
    f32x4* out4 = reinterpret_cast<f32x4*>(out);
    int idx = blockIdx.x * 256 + threadIdx.x;
    int stride = gridDim.x * 256;
    for (; idx < n4; idx += stride) {
        f32x4 v = in4[idx];
        float a = fmaxf(fmaxf(fabsf(v.x), fabsf(v.y)),
                        fmaxf(fabsf(v.z), fabsf(v.w)));
        float m = a;
        m = fmaxf(m, __shfl_xor(m, 1));
        m = fmaxf(m, __shfl_xor(m, 2));
        m = fmaxf(m, __shfl_xor(m, 4));
        float g = m;
        g = fmaxf(g, __shfl_xor(g, 8));
        g = fmaxf(g, __shfl_xor(g, 16));
        float s32f  = m + 1e-8f;
        float s128f = g + 1e-8f;
        f32x4 r;
        r.x = qdq_elem(v.x, s32f, s128f);
        r.y = qdq_elem(v.y, s32f, s128f);
        r.z = qdq_elem(v.z, s32f, s128f);
        r.w = qdq_elem(v.w, s32f, s128f);
        __builtin_nontemporal_store(r, &out4[idx]);
    }
}

extern "C" void kernel_launch(void* const* d_in, const int* in_sizes, int n_in,
                              void* d_out, int out_size, void* d_ws, size_t ws_size,
                              hipStream_t stream) {
    const float* x = (const float*)d_in[0];
    float* out = (float*)d_out;
    int n = in_sizes[0];              // 8192*8192 = 2^26
    int n4 = n / 4;                   // 2^24 float4 chunks
    const int blocks = 2048;          // 8 blocks/CU
    int lanes = blocks * 256;
    if (n4 % lanes == 0) {
        int iters = n4 / lanes;       // 32 for the bench shape
        hipLaunchKernelGGL(mx2q_kernel, dim3(blocks), dim3(256), 0, stream,
                           x, out, iters, lanes);
    } else {
        long long blocks_ll = ((long long)n4 + 255) / 256;
        int b = (int)(blocks_ll < 2048 ? blocks_ll : 2048);
        hipLaunchKernelGGL(mx2q_kernel_gs, dim3(b), dim3(256), 0, stream,
                           x, out, n4);
    }
}